// Round 9
// baseline (265.593 us; speedup 1.0000x reference)
//
#include <hip/hip_runtime.h>
#include <hip/hip_bf16.h>

// Problem constants (fixed by setup_inputs)
#define B 4
#define T 1024
#define D 512
#define U 32
#define WIN 64           // attention window (j in [t-32, t+31])
#define EPS 1e-7f

__device__ __forceinline__ float fast_tanh(float z) {
    const float ez = __expf(2.0f * z);
    return 1.0f - 2.0f / (ez + 1.0f);
}

__device__ __forceinline__ float bcast_lane(float v, int l) {
    return __int_as_float(__builtin_amdgcn_readlane(__float_as_int(v), l));
}

// ---------------------------------------------------------------------------
// Kernel A (v5 internals, x16 REPLICATED grid — DIAGNOSTIC ROUND).
// Grid 4096 = 16 identical copies of the 256-block kernel; every copy writes
// the same values to the same addresses (idempotent). Measured dur ~= 16x the
// true qk cost, forcing it into the rocprof top-5 for direct observation.
// ---------------------------------------------------------------------------
__global__ __launch_bounds__(512) void qk_kernel(
    const float* __restrict__ x, const float* __restrict__ Wt,
    const float* __restrict__ Wx, const float* __restrict__ bh,
    float* __restrict__ qk)
{
    __shared__ float W2[D][64];          // 128 KB: [d][0:32]=Wt, [32:64]=Wx

    const int tid  = threadIdx.x;
    const int lane = tid & 63;
    const int wv   = tid >> 6;           // 0..7
    const int blk  = blockIdx.x & 255;   // 16 replicas -> same 256 block ids
    const int r0   = blk * 16 + wv * 2;

    {
        const float4* Wt4 = (const float4*)Wt;
        const float4* Wx4 = (const float4*)Wx;
        #pragma unroll
        for (int i = 0; i < 8; ++i) {
            const int j  = i * 512 + tid;     // float4 index 0..4095
            const int d  = j >> 3;
            const int u0 = (j & 7) << 2;
            *(float4*)&W2[d][u0]      = Wt4[j];
            *(float4*)&W2[d][32 + u0] = Wx4[j];
        }
    }

    const float4* xr0 = (const float4*)(x + (size_t)(r0 + 0) * D);
    const float4* xr1 = (const float4*)(x + (size_t)(r0 + 1) * D);
    const float4 A0 = xr0[lane * 2], A1 = xr0[lane * 2 + 1];
    const float4 B0 = xr1[lane * 2], B1 = xr1[lane * 2 + 1];
    const float xa[8] = {A0.x, A0.y, A0.z, A0.w, A1.x, A1.y, A1.z, A1.w};
    const float xb[8] = {B0.x, B0.y, B0.z, B0.w, B1.x, B1.y, B1.z, B1.w};

    __syncthreads();

    const float bias = (lane < U) ? bh[lane] : 0.0f;
    float acc0 = bias, acc1 = bias;

    #pragma unroll
    for (int l = 0; l < 64; ++l) {
        #pragma unroll
        for (int r = 0; r < 8; ++r) {
            const float w  = W2[l * 8 + r][lane];
            const float s0 = bcast_lane(xa[r], l);
            const float s1 = bcast_lane(xb[r], l);
            acc0 = fmaf(s0, w, acc0);
            acc1 = fmaf(s1, w, acc1);
        }
    }

    qk[(size_t)(r0 + 0) * WIN + lane] = acc0;
    qk[(size_t)(r0 + 1) * WIN + lane] = acc1;
}

// ---------------------------------------------------------------------------
// Kernel B v3: quad-blocking. 512 blocks x 4 waves; block = 8 consecutive t
// (two quads of 4). Wave = (quad, d-half). Phase 1: wave scores 2 t's
// (lane = window pos), A[2][4][64] in LDS. Phase 2: wave accumulates 4
// outputs over 67 clamped branch-free rows — x traffic per t halved vs v2.
// XCD-chunked swizzle keeps each XCD's x slice L2-resident.
// ---------------------------------------------------------------------------
__global__ __launch_bounds__(256) void attn_kernel(
    const float* __restrict__ x, const float* __restrict__ qk,
    const float* __restrict__ Wa, const float* __restrict__ ba,
    float* __restrict__ out)
{
    __shared__ float A[2][4][64];        // [quadSlot][ti][j]

    const int tid  = threadIdx.x;
    const int lane = tid & 63;
    const int wv   = tid >> 6;                       // 0..3
    const int l    = ((blockIdx.x & 7) << 6) + (blockIdx.x >> 3);  // 0..511
    const int qs   = wv >> 1;                        // quad slot in block
    const int dh   = wv & 1;                         // d-half
    const int g0   = l * 8 + qs * 4;                 // quad base t (global)
    const int b    = g0 >> 10;
    const int t0   = g0 & (T - 1);                   // t0..t0+3 in this quad

    // ---- Phase 1: this wave scores ts = t0 + dh*2 + {0,1} ----
    #pragma unroll
    for (int i = 0; i < 2; ++i) {
        const int tt = t0 + dh * 2 + i;
        const float* qrow = qk + (size_t)(b * T + tt) * WIN;
        const int jj = tt - 32 + lane;
        float e = 0.0f;
        if (jj >= 0 && jj < T) {
            const float* krow = qk + (size_t)(b * T + jj) * WIN + U;
            float acc = ba[0];
            #pragma unroll
            for (int i4 = 0; i4 < 8; ++i4) {
                const float4 kv = ((const float4*)krow)[i4];
                const float4 qv = ((const float4*)qrow)[i4];
                acc = fmaf(Wa[i4 * 4 + 0], fast_tanh(qv.x + kv.x), acc);
                acc = fmaf(Wa[i4 * 4 + 1], fast_tanh(qv.y + kv.y), acc);
                acc = fmaf(Wa[i4 * 4 + 2], fast_tanh(qv.z + kv.z), acc);
                acc = fmaf(Wa[i4 * 4 + 3], fast_tanh(qv.w + kv.w), acc);
            }
            e = __expf(acc);
        }
        float s = e;
        #pragma unroll
        for (int off = 32; off > 0; off >>= 1)
            s += __shfl_xor(s, off);
        A[qs][dh * 2 + i][lane] = e / (s + EPS);
    }
    __syncthreads();

    // Weight vectors into registers (4 LDS reads; broadcast via readlane)
    const float w0 = A[qs][0][lane];
    const float w1 = A[qs][1][lane];
    const float w2 = A[qs][2][lane];
    const float w3 = A[qs][3][lane];

    // ---- Phase 2: union window rows t0-32 .. t0+34 (67 rows), branch-free --
    float4 v0 = make_float4(0.f,0.f,0.f,0.f), v1 = v0, v2 = v0, v3 = v0;
    const float* xh = x + (size_t)b * T * D + dh * (D / 2);

    #pragma unroll
    for (int m = 0; m < 67; ++m) {
        int row = t0 - 32 + m;
        row = (row < 0) ? 0 : row;
        row = (row > T - 1) ? (T - 1) : row;         // clamped: always safe
        const float4 xv = ((const float4*)(xh + (size_t)row * D))[lane];
        if (m <= 63) {
            const float a0 = bcast_lane(w0, m);
            v0.x = fmaf(a0, xv.x, v0.x); v0.y = fmaf(a0, xv.y, v0.y);
            v0.z = fmaf(a0, xv.z, v0.z); v0.w = fmaf(a0, xv.w, v0.w);
        }
        if (m >= 1 && m <= 64) {
            const float a1 = bcast_lane(w1, m - 1);
            v1.x = fmaf(a1, xv.x, v1.x); v1.y = fmaf(a1, xv.y, v1.y);
            v1.z = fmaf(a1, xv.z, v1.z); v1.w = fmaf(a1, xv.w, v1.w);
        }
        if (m >= 2 && m <= 65) {
            const float a2 = bcast_lane(w2, m - 2);
            v2.x = fmaf(a2, xv.x, v2.x); v2.y = fmaf(a2, xv.y, v2.y);
            v2.z = fmaf(a2, xv.z, v2.z); v2.w = fmaf(a2, xv.w, v2.w);
        }
        if (m >= 3) {
            const float a3 = bcast_lane(w3, m - 3);
            v3.x = fmaf(a3, xv.x, v3.x); v3.y = fmaf(a3, xv.y, v3.y);
            v3.z = fmaf(a3, xv.z, v3.z); v3.w = fmaf(a3, xv.w, v3.w);
        }
    }

    float* ob = out + (size_t)(b * T + t0) * D + dh * (D / 2);
    ((float4*)(ob + 0 * D))[lane] = v0;
    ((float4*)(ob + 1 * D))[lane] = v1;
    ((float4*)(ob + 2 * D))[lane] = v2;
    ((float4*)(ob + 3 * D))[lane] = v3;
}

extern "C" void kernel_launch(void* const* d_in, const int* in_sizes, int n_in,
                              void* d_out, int out_size, void* d_ws, size_t ws_size,
                              hipStream_t stream)
{
    const float* x  = (const float*)d_in[0];
    const float* Wt = (const float*)d_in[1];
    const float* Wx = (const float*)d_in[2];
    const float* bh = (const float*)d_in[3];
    const float* Wa = (const float*)d_in[4];
    const float* ba = (const float*)d_in[5];
    float* out = (float*)d_out;
    float* qk  = (float*)d_ws;   // B*T*64 floats = 1 MB

    // DIAGNOSTIC: 16 idempotent replicas of qk (grid 4096) to surface its
    // true per-launch cost in the rocprof top-5. Revert to 256 next round.
    qk_kernel<<<dim3(4096), dim3(512), 0, stream>>>(x, Wt, Wx, bh, qk);
    attn_kernel<<<dim3(512), dim3(256), 0, stream>>>(x, qk, Wa, ba, out);
}

// Round 10
// 115.524 us; speedup vs baseline: 2.2990x; 2.2990x over previous
//
#include <hip/hip_runtime.h>
#include <hip/hip_bf16.h>

// Problem constants (fixed by setup_inputs)
#define B 4
#define T 1024
#define D 512
#define U 32
#define WIN 64           // attention window (j in [t-32, t+31])
#define EPS 1e-7f

__device__ __forceinline__ float fast_tanh(float z) {
    const float ez = __expf(2.0f * z);
    return 1.0f - 2.0f / (ez + 1.0f);
}

__device__ __forceinline__ float bcast_lane(float v, int l) {
    return __int_as_float(__builtin_amdgcn_readlane(__float_as_int(v), l));
}

// ---------------------------------------------------------------------------
// Kernel A v6: lane = combined u (0:32 q, 32:64 k), 4 rows/wave.
// 256 blocks x 256 thr (4 waves), 16 rows/block. Full W in LDS (128 KB).
// KEY: row base hoisted to SGPR via readfirstlane -> x[row][d] loads are
// wave-uniform s_loads; FMA reads the scalar operand directly (no readlane,
// no broadcast VALU). Per d: 1 conflict-free ds_read_b32 + 4 FMA.
// ---------------------------------------------------------------------------
__global__ __launch_bounds__(256) void qk_kernel(
    const float* __restrict__ x, const float* __restrict__ Wt,
    const float* __restrict__ Wx, const float* __restrict__ bh,
    float* __restrict__ qk)
{
    __shared__ float W2[D][64];          // 128 KB: [d][0:32]=Wt, [32:64]=Wx

    const int tid  = threadIdx.x;
    const int lane = tid & 63;
    const int wv   = tid >> 6;           // 0..3
    // wave-uniform row base, forced into SGPR so x loads scalarize
    const int r0 = __builtin_amdgcn_readfirstlane(blockIdx.x * 16 + wv * 4);

    // ---- stage all of Wt|Wx into LDS (4096 float4 each, 16 per thread) ----
    {
        const float4* Wt4 = (const float4*)Wt;
        const float4* Wx4 = (const float4*)Wx;
        #pragma unroll
        for (int i = 0; i < 16; ++i) {
            const int j  = i * 256 + tid;     // float4 index 0..4095
            const int d  = j >> 3;
            const int u0 = (j & 7) << 2;
            *(float4*)&W2[d][u0]      = Wt4[j];
            *(float4*)&W2[d][32 + u0] = Wx4[j];
        }
    }
    __syncthreads();

    const float* x0 = x + (size_t)r0 * D;
    const float bias = (lane < U) ? bh[lane] : 0.0f;
    float a0 = bias, a1 = bias, a2 = bias, a3 = bias;

    #pragma unroll 8
    for (int d4 = 0; d4 < D / 4; ++d4) {
        // wave-uniform x loads (s_load candidates; L1/L2-hot)
        const float4 s0 = *(const float4*)(x0 + 0 * D + d4 * 4);
        const float4 s1 = *(const float4*)(x0 + 1 * D + d4 * 4);
        const float4 s2 = *(const float4*)(x0 + 2 * D + d4 * 4);
        const float4 s3 = *(const float4*)(x0 + 3 * D + d4 * 4);

        const float w0 = W2[d4 * 4 + 0][lane];
        const float w1 = W2[d4 * 4 + 1][lane];
        const float w2 = W2[d4 * 4 + 2][lane];
        const float w3 = W2[d4 * 4 + 3][lane];

        a0 = fmaf(s0.x, w0, a0); a1 = fmaf(s1.x, w0, a1);
        a2 = fmaf(s2.x, w0, a2); a3 = fmaf(s3.x, w0, a3);
        a0 = fmaf(s0.y, w1, a0); a1 = fmaf(s1.y, w1, a1);
        a2 = fmaf(s2.y, w1, a2); a3 = fmaf(s3.y, w1, a3);
        a0 = fmaf(s0.z, w2, a0); a1 = fmaf(s1.z, w2, a1);
        a2 = fmaf(s2.z, w2, a2); a3 = fmaf(s3.z, w2, a3);
        a0 = fmaf(s0.w, w3, a0); a1 = fmaf(s1.w, w3, a1);
        a2 = fmaf(s2.w, w3, a2); a3 = fmaf(s3.w, w3, a3);
    }

    qk[(size_t)(r0 + 0) * WIN + lane] = a0;
    qk[(size_t)(r0 + 1) * WIN + lane] = a1;
    qk[(size_t)(r0 + 2) * WIN + lane] = a2;
    qk[(size_t)(r0 + 3) * WIN + lane] = a3;
}

// ---------------------------------------------------------------------------
// Kernel B v4: octo-blocking + explicit double-buffered load pipeline.
// 256 blocks x 4 waves; block = 16 t (2 octos x 2 d-halves). Phase 1: wave
// scores 4 t's. Phase 2: wave produces 8 outputs over its 256-wide d-half,
// streaming 71 clamped rows in groups of 4 with bufA/bufB prefetch (all
// indices static -> registers, loads batched 4-deep ahead of use).
// ---------------------------------------------------------------------------
__global__ __launch_bounds__(256) void attn_kernel(
    const float* __restrict__ x, const float* __restrict__ qk,
    const float* __restrict__ Wa, const float* __restrict__ ba,
    float* __restrict__ out)
{
    __shared__ float A[2][8][64];        // [octoSlot][r][j]  4 KB

    const int tid  = threadIdx.x;
    const int lane = tid & 63;
    const int wv   = tid >> 6;                       // 0..3
    const int l    = ((blockIdx.x & 7) << 5) + (blockIdx.x >> 3);  // XCD chunk
    const int os   = wv >> 1;                        // octo slot in block
    const int dh   = wv & 1;                         // d-half
    const int g0   = l * 16 + os * 8;                // global base row of octo
    const int b    = g0 >> 10;
    const int t0   = g0 & (T - 1);                   // local base t (mult of 8)

    // ---- Phase 1: this wave scores tt = t0 + dh*4 + {0..3} ----
    #pragma unroll
    for (int i = 0; i < 4; ++i) {
        const int tt = t0 + dh * 4 + i;
        const float* qrow = qk + (size_t)(b * T + tt) * WIN;
        const int jj = tt - 32 + lane;
        float e = 0.0f;
        if (jj >= 0 && jj < T) {
            const float* krow = qk + (size_t)(b * T + jj) * WIN + U;
            float acc = ba[0];
            #pragma unroll
            for (int i4 = 0; i4 < 8; ++i4) {
                const float4 kv = ((const float4*)krow)[i4];
                const float4 qv = ((const float4*)qrow)[i4];
                acc = fmaf(Wa[i4 * 4 + 0], fast_tanh(qv.x + kv.x), acc);
                acc = fmaf(Wa[i4 * 4 + 1], fast_tanh(qv.y + kv.y), acc);
                acc = fmaf(Wa[i4 * 4 + 2], fast_tanh(qv.z + kv.z), acc);
                acc = fmaf(Wa[i4 * 4 + 3], fast_tanh(qv.w + kv.w), acc);
            }
            e = __expf(acc);
        }
        float s = e;
        #pragma unroll
        for (int off = 32; off > 0; off >>= 1)
            s += __shfl_xor(s, off);
        A[os][dh * 4 + i][lane] = e / (s + EPS);
    }
    __syncthreads();

    // Weight vectors into registers (8 LDS reads; broadcast via readlane)
    float w[8];
    #pragma unroll
    for (int r = 0; r < 8; ++r) w[r] = A[os][r][lane];

    // ---- Phase 2: rows t0-32 .. t0+38 (71 rows, padded to 72) ----
    float4 acc[8];
    #pragma unroll
    for (int r = 0; r < 8; ++r) acc[r] = make_float4(0.f, 0.f, 0.f, 0.f);

    const float* xh = x + (size_t)b * T * D + dh * (D / 2);

#define LOADG(buf, g)                                                         \
    _Pragma("unroll")                                                         \
    for (int ii = 0; ii < 4; ++ii) {                                          \
        int lr = t0 - 32 + (g) * 4 + ii;                                      \
        lr = (lr < 0) ? 0 : lr;                                               \
        lr = (lr > T - 1) ? (T - 1) : lr;                                     \
        buf[ii] = ((const float4*)(xh + (size_t)lr * D))[lane];               \
    }

#define FMAG(buf, g)                                                          \
    _Pragma("unroll")                                                         \
    for (int ii = 0; ii < 4; ++ii) {                                          \
        const int m = (g) * 4 + ii;                                           \
        _Pragma("unroll")                                                     \
        for (int r = 0; r < 8; ++r) {                                         \
            if (m <= 70 && m - r >= 0 && m - r <= 63) {                       \
                const float aw = bcast_lane(w[r], m - r);                     \
                acc[r].x = fmaf(aw, buf[ii].x, acc[r].x);                     \
                acc[r].y = fmaf(aw, buf[ii].y, acc[r].y);                     \
                acc[r].z = fmaf(aw, buf[ii].z, acc[r].z);                     \
                acc[r].w = fmaf(aw, buf[ii].w, acc[r].w);                     \
            }                                                                 \
        }                                                                     \
    }

    float4 bufA[4], bufB[4];
    LOADG(bufA, 0)
    #pragma unroll
    for (int g = 0; g < 18; ++g) {
        if (g & 1) {
            if (g < 17) { LOADG(bufA, g + 1) }
            FMAG(bufB, g)
        } else {
            if (g < 17) { LOADG(bufB, g + 1) }
            FMAG(bufA, g)
        }
    }
#undef LOADG
#undef FMAG

    float* ob = out + (size_t)(b * T + t0) * D + dh * (D / 2);
    #pragma unroll
    for (int r = 0; r < 8; ++r)
        ((float4*)(ob + (size_t)r * D))[lane] = acc[r];
}

extern "C" void kernel_launch(void* const* d_in, const int* in_sizes, int n_in,
                              void* d_out, int out_size, void* d_ws, size_t ws_size,
                              hipStream_t stream)
{
    const float* x  = (const float*)d_in[0];
    const float* Wt = (const float*)d_in[1];
    const float* Wx = (const float*)d_in[2];
    const float* bh = (const float*)d_in[3];
    const float* Wa = (const float*)d_in[4];
    const float* ba = (const float*)d_in[5];
    float* out = (float*)d_out;
    float* qk  = (float*)d_ws;   // B*T*64 floats = 1 MB

    qk_kernel<<<dim3(256), dim3(256), 0, stream>>>(x, Wt, Wx, bh, qk);
    attn_kernel<<<dim3(256), dim3(256), 0, stream>>>(x, qk, Wa, ba, out);
}

// Round 11
// 95.383 us; speedup vs baseline: 2.7845x; 1.2112x over previous
//
#include <hip/hip_runtime.h>
#include <hip/hip_bf16.h>

// Problem constants (fixed by setup_inputs)
#define B 4
#define T 1024
#define D 512
#define U 32
#define WIN 64           // attention window (j in [t-32, t+31])
#define EPS 1e-7f

__device__ __forceinline__ float fast_tanh(float z) {
    const float ez = __expf(2.0f * z);
    return 1.0f - 2.0f / (ez + 1.0f);
}

__device__ __forceinline__ float bcast_lane(float v, int l) {
    return __int_as_float(__builtin_amdgcn_readlane(__float_as_int(v), l));
}

// ---------------------------------------------------------------------------
// Kernel A v5 (CHECKPOINT: directly measured 12.5 us in round-9 x16 diag).
// 256 blocks x 512 thr (8 waves), 2 rows/wave. Full W (128 KB) in LDS.
// Lane's x slice in registers; K-loop broadcasts x[d] via readlane.
// ---------------------------------------------------------------------------
__global__ __launch_bounds__(512) void qk_kernel(
    const float* __restrict__ x, const float* __restrict__ Wt,
    const float* __restrict__ Wx, const float* __restrict__ bh,
    float* __restrict__ qk)
{
    __shared__ float W2[D][64];          // 128 KB: [d][0:32]=Wt, [32:64]=Wx

    const int tid  = threadIdx.x;
    const int lane = tid & 63;
    const int wv   = tid >> 6;           // 0..7
    const int r0   = blockIdx.x * 16 + wv * 2;

    {
        const float4* Wt4 = (const float4*)Wt;
        const float4* Wx4 = (const float4*)Wx;
        #pragma unroll
        for (int i = 0; i < 8; ++i) {
            const int j  = i * 512 + tid;     // float4 index 0..4095
            const int d  = j >> 3;
            const int u0 = (j & 7) << 2;
            *(float4*)&W2[d][u0]      = Wt4[j];
            *(float4*)&W2[d][32 + u0] = Wx4[j];
        }
    }

    const float4* xr0 = (const float4*)(x + (size_t)(r0 + 0) * D);
    const float4* xr1 = (const float4*)(x + (size_t)(r0 + 1) * D);
    const float4 A0 = xr0[lane * 2], A1 = xr0[lane * 2 + 1];
    const float4 B0 = xr1[lane * 2], B1 = xr1[lane * 2 + 1];
    const float xa[8] = {A0.x, A0.y, A0.z, A0.w, A1.x, A1.y, A1.z, A1.w};
    const float xb[8] = {B0.x, B0.y, B0.z, B0.w, B1.x, B1.y, B1.z, B1.w};

    __syncthreads();

    const float bias = (lane < U) ? bh[lane] : 0.0f;
    float acc0 = bias, acc1 = bias;

    #pragma unroll
    for (int l = 0; l < 64; ++l) {
        #pragma unroll
        for (int r = 0; r < 8; ++r) {
            const float w  = W2[l * 8 + r][lane];
            const float s0 = bcast_lane(xa[r], l);
            const float s1 = bcast_lane(xb[r], l);
            acc0 = fmaf(s0, w, acc0);
            acc1 = fmaf(s1, w, acc1);
        }
    }

    qk[(size_t)(r0 + 0) * WIN + lane] = acc0;
    qk[(size_t)(r0 + 1) * WIN + lane] = acc1;
}

// ---------------------------------------------------------------------------
// Kernel B v3 (CHECKPOINT: inferred 19.6 us from round-9). Quad-blocking,
// 512 blocks x 4 waves (2 blocks/CU), branch-free clamped phase 2.
// ---------------------------------------------------------------------------
__global__ __launch_bounds__(256) void attn_kernel(
    const float* __restrict__ x, const float* __restrict__ qk,
    const float* __restrict__ Wa, const float* __restrict__ ba,
    float* __restrict__ out)
{
    __shared__ float A[2][4][64];        // [quadSlot][ti][j]

    const int tid  = threadIdx.x;
    const int lane = tid & 63;
    const int wv   = tid >> 6;                       // 0..3
    const int l    = ((blockIdx.x & 7) << 6) + (blockIdx.x >> 3);  // 0..511
    const int qs   = wv >> 1;                        // quad slot in block
    const int dh   = wv & 1;                         // d-half
    const int g0   = l * 8 + qs * 4;                 // quad base t (global)
    const int b    = g0 >> 10;
    const int t0   = g0 & (T - 1);                   // t0..t0+3 in this quad

    // ---- Phase 1: this wave scores ts = t0 + dh*2 + {0,1} ----
    #pragma unroll
    for (int i = 0; i < 2; ++i) {
        const int tt = t0 + dh * 2 + i;
        const float* qrow = qk + (size_t)(b * T + tt) * WIN;
        const int jj = tt - 32 + lane;
        float e = 0.0f;
        if (jj >= 0 && jj < T) {
            const float* krow = qk + (size_t)(b * T + jj) * WIN + U;
            float acc = ba[0];
            #pragma unroll
            for (int i4 = 0; i4 < 8; ++i4) {
                const float4 kv = ((const float4*)krow)[i4];
                const float4 qv = ((const float4*)qrow)[i4];
                acc = fmaf(Wa[i4 * 4 + 0], fast_tanh(qv.x + kv.x), acc);
                acc = fmaf(Wa[i4 * 4 + 1], fast_tanh(qv.y + kv.y), acc);
                acc = fmaf(Wa[i4 * 4 + 2], fast_tanh(qv.z + kv.z), acc);
                acc = fmaf(Wa[i4 * 4 + 3], fast_tanh(qv.w + kv.w), acc);
            }
            e = __expf(acc);
        }
        float s = e;
        #pragma unroll
        for (int off = 32; off > 0; off >>= 1)
            s += __shfl_xor(s, off);
        A[qs][dh * 2 + i][lane] = e / (s + EPS);
    }
    __syncthreads();

    const float w0 = A[qs][0][lane];
    const float w1 = A[qs][1][lane];
    const float w2 = A[qs][2][lane];
    const float w3 = A[qs][3][lane];

    // ---- Phase 2: union window rows t0-32 .. t0+34 (67 rows), branch-free --
    float4 v0 = make_float4(0.f,0.f,0.f,0.f), v1 = v0, v2 = v0, v3 = v0;
    const float* xh = x + (size_t)b * T * D + dh * (D / 2);

    #pragma unroll
    for (int m = 0; m < 67; ++m) {
        int row = t0 - 32 + m;
        row = (row < 0) ? 0 : row;
        row = (row > T - 1) ? (T - 1) : row;         // clamped: always safe
        const float4 xv = ((const float4*)(xh + (size_t)row * D))[lane];
        if (m <= 63) {
            const float a0 = bcast_lane(w0, m);
            v0.x = fmaf(a0, xv.x, v0.x); v0.y = fmaf(a0, xv.y, v0.y);
            v0.z = fmaf(a0, xv.z, v0.z); v0.w = fmaf(a0, xv.w, v0.w);
        }
        if (m >= 1 && m <= 64) {
            const float a1 = bcast_lane(w1, m - 1);
            v1.x = fmaf(a1, xv.x, v1.x); v1.y = fmaf(a1, xv.y, v1.y);
            v1.z = fmaf(a1, xv.z, v1.z); v1.w = fmaf(a1, xv.w, v1.w);
        }
        if (m >= 2 && m <= 65) {
            const float a2 = bcast_lane(w2, m - 2);
            v2.x = fmaf(a2, xv.x, v2.x); v2.y = fmaf(a2, xv.y, v2.y);
            v2.z = fmaf(a2, xv.z, v2.z); v2.w = fmaf(a2, xv.w, v2.w);
        }
        if (m >= 3) {
            const float a3 = bcast_lane(w3, m - 3);
            v3.x = fmaf(a3, xv.x, v3.x); v3.y = fmaf(a3, xv.y, v3.y);
            v3.z = fmaf(a3, xv.z, v3.z); v3.w = fmaf(a3, xv.w, v3.w);
        }
    }

    float* ob = out + (size_t)(b * T + t0) * D + dh * (D / 2);
    ((float4*)(ob + 0 * D))[lane] = v0;
    ((float4*)(ob + 1 * D))[lane] = v1;
    ((float4*)(ob + 2 * D))[lane] = v2;
    ((float4*)(ob + 3 * D))[lane] = v3;
}

extern "C" void kernel_launch(void* const* d_in, const int* in_sizes, int n_in,
                              void* d_out, int out_size, void* d_ws, size_t ws_size,
                              hipStream_t stream)
{
    const float* x  = (const float*)d_in[0];
    const float* Wt = (const float*)d_in[1];
    const float* Wx = (const float*)d_in[2];
    const float* bh = (const float*)d_in[3];
    const float* Wa = (const float*)d_in[4];
    const float* ba = (const float*)d_in[5];
    float* out = (float*)d_out;
    float* qk  = (float*)d_ws;   // B*T*64 floats = 1 MB

    qk_kernel<<<dim3(256), dim3(512), 0, stream>>>(x, Wt, Wx, bh, qk);
    attn_kernel<<<dim3(512), dim3(256), 0, stream>>>(x, qk, Wa, ba, out);
}

// Round 12
// 93.194 us; speedup vs baseline: 2.8499x; 1.0235x over previous
//
#include <hip/hip_runtime.h>
#include <hip/hip_bf16.h>

// Problem constants (fixed by setup_inputs)
#define B 4
#define T 1024
#define D 512
#define U 32
#define WIN 64           // attention window (j in [t-32, t+31])
#define EPS 1e-7f

__device__ __forceinline__ float fast_tanh(float z) {
    const float ez = __expf(2.0f * z);
    return 1.0f - 2.0f / (ez + 1.0f);
}

__device__ __forceinline__ float bcast_lane(float v, int l) {
    return __int_as_float(__builtin_amdgcn_readlane(__float_as_int(v), l));
}

// ---------------------------------------------------------------------------
// Kernel A v5.1: identical compute to v5 (measured 12.5 us), but block->row
// mapping is XCD-CHUNK ALIGNED with attn's swizzle: block bid (XCD = bid%8)
// covers rows (bid%8)*512 + (bid/8)*16 .. +16. Effect: XCD c's L2 is left
// warm with exactly x rows [512c, 512c+512) and the matching qk slice --
// the precise working set attn's blocks on XCD c will read. This converts
// attn's cross-XCD L3-latency misses into L2 hits (the round-9 warm-cache
// effect, now deliberate).
// ---------------------------------------------------------------------------
__global__ __launch_bounds__(512) void qk_kernel(
    const float* __restrict__ x, const float* __restrict__ Wt,
    const float* __restrict__ Wx, const float* __restrict__ bh,
    float* __restrict__ qk)
{
    __shared__ float W2[D][64];          // 128 KB: [d][0:32]=Wt, [32:64]=Wx

    const int tid  = threadIdx.x;
    const int lane = tid & 63;
    const int wv   = tid >> 6;           // 0..7
    const int bid  = blockIdx.x;
    // XCD-chunk-aligned row base (was: bid * 16 + wv * 2)
    const int r0   = (bid & 7) * 512 + (bid >> 3) * 16 + wv * 2;

    {
        const float4* Wt4 = (const float4*)Wt;
        const float4* Wx4 = (const float4*)Wx;
        #pragma unroll
        for (int i = 0; i < 8; ++i) {
            const int j  = i * 512 + tid;     // float4 index 0..4095
            const int d  = j >> 3;
            const int u0 = (j & 7) << 2;
            *(float4*)&W2[d][u0]      = Wt4[j];
            *(float4*)&W2[d][32 + u0] = Wx4[j];
        }
    }

    const float4* xr0 = (const float4*)(x + (size_t)(r0 + 0) * D);
    const float4* xr1 = (const float4*)(x + (size_t)(r0 + 1) * D);
    const float4 A0 = xr0[lane * 2], A1 = xr0[lane * 2 + 1];
    const float4 B0 = xr1[lane * 2], B1 = xr1[lane * 2 + 1];
    const float xa[8] = {A0.x, A0.y, A0.z, A0.w, A1.x, A1.y, A1.z, A1.w};
    const float xb[8] = {B0.x, B0.y, B0.z, B0.w, B1.x, B1.y, B1.z, B1.w};

    __syncthreads();

    const float bias = (lane < U) ? bh[lane] : 0.0f;
    float acc0 = bias, acc1 = bias;

    #pragma unroll
    for (int l = 0; l < 64; ++l) {
        #pragma unroll
        for (int r = 0; r < 8; ++r) {
            const float w  = W2[l * 8 + r][lane];
            const float s0 = bcast_lane(xa[r], l);
            const float s1 = bcast_lane(xb[r], l);
            acc0 = fmaf(s0, w, acc0);
            acc1 = fmaf(s1, w, acc1);
        }
    }

    qk[(size_t)(r0 + 0) * WIN + lane] = acc0;
    qk[(size_t)(r0 + 1) * WIN + lane] = acc1;
}

// ---------------------------------------------------------------------------
// Kernel B v3 (UNCHANGED — single-variable round). Quad-blocking, 512 blocks
// x 4 waves, XCD-chunked swizzle, branch-free clamped phase 2.
// ---------------------------------------------------------------------------
__global__ __launch_bounds__(256) void attn_kernel(
    const float* __restrict__ x, const float* __restrict__ qk,
    const float* __restrict__ Wa, const float* __restrict__ ba,
    float* __restrict__ out)
{
    __shared__ float A[2][4][64];        // [quadSlot][ti][j]

    const int tid  = threadIdx.x;
    const int lane = tid & 63;
    const int wv   = tid >> 6;                       // 0..3
    const int l    = ((blockIdx.x & 7) << 6) + (blockIdx.x >> 3);  // 0..511
    const int qs   = wv >> 1;                        // quad slot in block
    const int dh   = wv & 1;                         // d-half
    const int g0   = l * 8 + qs * 4;                 // quad base t (global)
    const int b    = g0 >> 10;
    const int t0   = g0 & (T - 1);                   // t0..t0+3 in this quad

    // ---- Phase 1: this wave scores ts = t0 + dh*2 + {0,1} ----
    #pragma unroll
    for (int i = 0; i < 2; ++i) {
        const int tt = t0 + dh * 2 + i;
        const float* qrow = qk + (size_t)(b * T + tt) * WIN;
        const int jj = tt - 32 + lane;
        float e = 0.0f;
        if (jj >= 0 && jj < T) {
            const float* krow = qk + (size_t)(b * T + jj) * WIN + U;
            float acc = ba[0];
            #pragma unroll
            for (int i4 = 0; i4 < 8; ++i4) {
                const float4 kv = ((const float4*)krow)[i4];
                const float4 qv = ((const float4*)qrow)[i4];
                acc = fmaf(Wa[i4 * 4 + 0], fast_tanh(qv.x + kv.x), acc);
                acc = fmaf(Wa[i4 * 4 + 1], fast_tanh(qv.y + kv.y), acc);
                acc = fmaf(Wa[i4 * 4 + 2], fast_tanh(qv.z + kv.z), acc);
                acc = fmaf(Wa[i4 * 4 + 3], fast_tanh(qv.w + kv.w), acc);
            }
            e = __expf(acc);
        }
        float s = e;
        #pragma unroll
        for (int off = 32; off > 0; off >>= 1)
            s += __shfl_xor(s, off);
        A[qs][dh * 2 + i][lane] = e / (s + EPS);
    }
    __syncthreads();

    const float w0 = A[qs][0][lane];
    const float w1 = A[qs][1][lane];
    const float w2 = A[qs][2][lane];
    const float w3 = A[qs][3][lane];

    // ---- Phase 2: union window rows t0-32 .. t0+34 (67 rows), branch-free --
    float4 v0 = make_float4(0.f,0.f,0.f,0.f), v1 = v0, v2 = v0, v3 = v0;
    const float* xh = x + (size_t)b * T * D + dh * (D / 2);

    #pragma unroll
    for (int m = 0; m < 67; ++m) {
        int row = t0 - 32 + m;
        row = (row < 0) ? 0 : row;
        row = (row > T - 1) ? (T - 1) : row;         // clamped: always safe
        const float4 xv = ((const float4*)(xh + (size_t)row * D))[lane];
        if (m <= 63) {
            const float a0 = bcast_lane(w0, m);
            v0.x = fmaf(a0, xv.x, v0.x); v0.y = fmaf(a0, xv.y, v0.y);
            v0.z = fmaf(a0, xv.z, v0.z); v0.w = fmaf(a0, xv.w, v0.w);
        }
        if (m >= 1 && m <= 64) {
            const float a1 = bcast_lane(w1, m - 1);
            v1.x = fmaf(a1, xv.x, v1.x); v1.y = fmaf(a1, xv.y, v1.y);
            v1.z = fmaf(a1, xv.z, v1.z); v1.w = fmaf(a1, xv.w, v1.w);
        }
        if (m >= 2 && m <= 65) {
            const float a2 = bcast_lane(w2, m - 2);
            v2.x = fmaf(a2, xv.x, v2.x); v2.y = fmaf(a2, xv.y, v2.y);
            v2.z = fmaf(a2, xv.z, v2.z); v2.w = fmaf(a2, xv.w, v2.w);
        }
        if (m >= 3) {
            const float a3 = bcast_lane(w3, m - 3);
            v3.x = fmaf(a3, xv.x, v3.x); v3.y = fmaf(a3, xv.y, v3.y);
            v3.z = fmaf(a3, xv.z, v3.z); v3.w = fmaf(a3, xv.w, v3.w);
        }
    }

    float* ob = out + (size_t)(b * T + t0) * D + dh * (D / 2);
    ((float4*)(ob + 0 * D))[lane] = v0;
    ((float4*)(ob + 1 * D))[lane] = v1;
    ((float4*)(ob + 2 * D))[lane] = v2;
    ((float4*)(ob + 3 * D))[lane] = v3;
}

extern "C" void kernel_launch(void* const* d_in, const int* in_sizes, int n_in,
                              void* d_out, int out_size, void* d_ws, size_t ws_size,
                              hipStream_t stream)
{
    const float* x  = (const float*)d_in[0];
    const float* Wt = (const float*)d_in[1];
    const float* Wx = (const float*)d_in[2];
    const float* bh = (const float*)d_in[3];
    const float* Wa = (const float*)d_in[4];
    const float* ba = (const float*)d_in[5];
    float* out = (float*)d_out;
    float* qk  = (float*)d_ws;   // B*T*64 floats = 1 MB

    qk_kernel<<<dim3(256), dim3(512), 0, stream>>>(x, Wt, Wx, bh, qk);
    attn_kernel<<<dim3(512), dim3(256), 0, stream>>>(x, qk, Wa, ba, out);
}